// Round 13
// baseline (361.038 us; speedup 1.0000x reference)
//
#include <hip/hip_runtime.h>

#define D 512
#define H1 1024
#define NNODES 50000
#define NEDGES 400000
#define MPAD 50176   // 392 * 128
#define NEG_SLOPE 0.2f
#define SCAN_BLOCKS 196   // 196*256 = 50176 >= 50000

// prep kernel block partition
#define NB_ND 12500   // nodedot: 50000 waves
#define NB_CW 2048    // convw: 524288 elems
#define NB_HI 1563    // hist: 400128 threads

typedef __attribute__((ext_vector_type(8))) short bf16x8;
typedef __attribute__((ext_vector_type(8))) unsigned short u16x8;
typedef __attribute__((ext_vector_type(16))) float f32x16;

// packed operand layout for GEMM staging:
// addr(r, k) = ((r>>7)*(K>>3) + (k>>3))*1024 + (r&127)*8 + (k&7)
// -> a 64-lane global_load_lds segment (64 rows x one 8-k chunk) is one
//    contiguous 1KB burst; LDS image is linear and conflict-free.

__device__ __forceinline__ unsigned short f2bf(float f) {
  unsigned int u = __float_as_uint(f);
  unsigned int r = u + 0x7FFFu + ((u >> 16) & 1u);
  return (unsigned short)(r >> 16);
}
__device__ __forceinline__ float bf2f(unsigned short h) {
  return __uint_as_float((unsigned int)h << 16);
}

__device__ __forceinline__ void gl_lds16(const void* g, void* l) {
  __builtin_amdgcn_global_load_lds(
      (const __attribute__((address_space(1))) void*)g,
      (__attribute__((address_space(3))) void*)l, 16, 0, 0);
}

// key[j] = sum_i cond[i] * Wk[i][j],  Wk is (256, 2D) row-major
__global__ void key_kernel(const float* __restrict__ cond, const float* __restrict__ Wk,
                           float* __restrict__ key) {
  int j = blockIdx.x * blockDim.x + threadIdx.x;
  if (j >= 2 * D) return;
  float s = 0.f;
#pragma unroll 8
  for (int i = 0; i < 256; ++i) s += cond[i] * Wk[i * (2 * D) + j];
  key[j] = s;
}

// fused independent pre-work: nodedot | convw | hist  (key must be done; deg zeroed)
__global__ __launch_bounds__(256) void prep_kernel(
    const float* __restrict__ x, const float* __restrict__ key,
    const float* __restrict__ W1, const float* __restrict__ W2,
    const int* __restrict__ row,
    float* __restrict__ nki, float* __restrict__ nkj, unsigned short* __restrict__ xb,
    unsigned short* __restrict__ W1t, unsigned short* __restrict__ W2t,
    int* __restrict__ deg) {
  const int b = blockIdx.x;
  const int tid = threadIdx.x;
  if (b < NB_ND) {
    // ---- nodedot: one wave per node; also emit xb = bf16(x) row-major ----
    int wid = (b * 256 + tid) >> 6;
    int lane = tid & 63;
    const float4* xr = (const float4*)(x + (size_t)wid * D);
    float4 p0 = xr[2 * lane], p1 = xr[2 * lane + 1];
    const float4* kia = (const float4*)key;
    const float4* kja = (const float4*)(key + D);
    float4 q0 = kia[2 * lane], q1 = kia[2 * lane + 1];
    float4 r0 = kja[2 * lane], r1 = kja[2 * lane + 1];
    float a = p0.x * q0.x + p0.y * q0.y + p0.z * q0.z + p0.w * q0.w +
              p1.x * q1.x + p1.y * q1.y + p1.z * q1.z + p1.w * q1.w;
    float bb = p0.x * r0.x + p0.y * r0.y + p0.z * r0.z + p0.w * r0.w +
               p1.x * r1.x + p1.y * r1.y + p1.z * r1.z + p1.w * r1.w;
    u16x8 h;
    h[0] = f2bf(p0.x); h[1] = f2bf(p0.y); h[2] = f2bf(p0.z); h[3] = f2bf(p0.w);
    h[4] = f2bf(p1.x); h[5] = f2bf(p1.y); h[6] = f2bf(p1.z); h[7] = f2bf(p1.w);
    *(u16x8*)(xb + (size_t)wid * D + 8 * lane) = h;
#pragma unroll
    for (int off = 32; off > 0; off >>= 1) {
      a += __shfl_xor(a, off);
      bb += __shfl_xor(bb, off);
    }
    if (lane == 0) { nki[wid] = a; nkj[wid] = bb; }
  } else if (b < NB_ND + NB_CW) {
    // ---- convw: W1 -> W1t packed (R=H1,K=D); W2 -> W2t packed (R=D,K=H1) ----
    int idx = (b - NB_ND) * 256 + tid;
    {
      int k = idx / H1, n = idx % H1;
      size_t a = (((size_t)(n >> 7) * (D >> 3) + (k >> 3)) << 10) + ((n & 127) << 3) + (k & 7);
      W1t[a] = f2bf(W1[idx]);
    }
    {
      int k = idx / D, n = idx % D;
      size_t a = (((size_t)(n >> 7) * (H1 >> 3) + (k >> 3)) << 10) + ((n & 127) << 3) + (k & 7);
      W2t[a] = f2bf(W2[idx]);
    }
  } else {
    // ---- hist ----
    int e = (b - NB_ND - NB_CW) * 256 + tid;
    if (e < NEDGES) atomicAdd(&deg[row[e]], 1);
  }
}

// ---- CSR scans ----
__global__ void scan1_kernel(const int* __restrict__ deg, int* __restrict__ rowptr,
                             int* __restrict__ blktot) {
  __shared__ int s[256];
  int tid = threadIdx.x;
  int i = blockIdx.x * 256 + tid;
  int v = (i < NNODES) ? deg[i] : 0;
  s[tid] = v;
  __syncthreads();
#pragma unroll
  for (int off = 1; off < 256; off <<= 1) {
    int t = (tid >= off) ? s[tid - off] : 0;
    __syncthreads();
    s[tid] += t;
    __syncthreads();
  }
  if (i < NNODES) rowptr[i] = s[tid] - v;
  if (tid == 255) blktot[blockIdx.x] = s[255];
}

// fused scan2+scan3: every block redundantly scans the 196 block totals,
// takes its own exclusive offset, applies to rowptr and inits cursor.
__global__ void scan23_kernel(int* __restrict__ rowptr, const int* __restrict__ blktot,
                              int* __restrict__ cursor) {
  __shared__ int s[256];
  int tid = threadIdx.x;
  int v = (tid < SCAN_BLOCKS) ? blktot[tid] : 0;
  s[tid] = v;
  __syncthreads();
#pragma unroll
  for (int off = 1; off < 256; off <<= 1) {
    int t = (tid >= off) ? s[tid - off] : 0;
    __syncthreads();
    s[tid] += t;
    __syncthreads();
  }
  const int blkoff = s[blockIdx.x] - blktot[blockIdx.x];  // exclusive
  int i = blockIdx.x * 256 + tid;
  if (i < NNODES) {
    int val = rowptr[i] + blkoff;
    rowptr[i] = val;
    cursor[i] = val;
  }
  if (i == 0) rowptr[NNODES] = NEDGES;
}

// fill: pure permutation — place col into CSR slot of its row
__global__ void fill_kernel(const int* __restrict__ row, const int* __restrict__ col,
                            int* __restrict__ cursor, int* __restrict__ scol) {
  int e = blockIdx.x * blockDim.x + threadIdx.x;
  if (e >= NEDGES) return;
  int pos = atomicAdd(&cursor[row[e]], 1);
  scol[pos] = col[e];
}

// one wave per node: Pb[n] = bf16(xb[n] + sum_e sigmoid(leaky(nki[c]+nkj[n])) * xb[c])
__global__ __launch_bounds__(256) void agg_kernel(
    const unsigned short* __restrict__ xb, const int* __restrict__ rowptr,
    const int* __restrict__ scol, const float* __restrict__ nki,
    const float* __restrict__ nkj, unsigned short* __restrict__ Pb) {
  int n = (blockIdx.x * blockDim.x + threadIdx.x) >> 6;
  int lane = threadIdx.x & 63;
  if (n >= NNODES) return;
  int beg = rowptr[n], end = rowptr[n + 1];
  const float nkjn = nkj[n];
  u16x8 self = *(const u16x8*)(xb + (size_t)n * D + 8 * lane);
  float sa[8], sb[8];
#pragma unroll
  for (int q = 0; q < 8; ++q) { sa[q] = bf2f(self[q]); sb[q] = 0.f; }
  auto alpha = [&](int c) {
    float a = nki[c] + nkjn;
    a = (a >= 0.f) ? a : NEG_SLOPE * a;
    return 1.f / (1.f + expf(-a));
  };
  int e = beg;
  for (; e + 1 < end; e += 2) {
    int c0 = scol[e], c1 = scol[e + 1];
    u16x8 w0 = *(const u16x8*)(xb + (size_t)c0 * D + 8 * lane);
    u16x8 w1 = *(const u16x8*)(xb + (size_t)c1 * D + 8 * lane);
    float al0 = alpha(c0), al1 = alpha(c1);
#pragma unroll
    for (int q = 0; q < 8; ++q) {
      sa[q] += al0 * bf2f(w0[q]);
      sb[q] += al1 * bf2f(w1[q]);
    }
  }
  if (e < end) {
    int c0 = scol[e];
    u16x8 w0 = *(const u16x8*)(xb + (size_t)c0 * D + 8 * lane);
    float al0 = alpha(c0);
#pragma unroll
    for (int q = 0; q < 8; ++q) sa[q] += al0 * bf2f(w0[q]);
  }
  u16x8 h;
#pragma unroll
  for (int q = 0; q < 8; ++q) h[q] = f2bf(sa[q] + sb[q]);
  *(u16x8*)(Pb + (((size_t)(n >> 7) * (D >> 3) + lane) << 10) + ((n & 127) << 3)) = h;
}

// ---- GEMM (m97 structure, 32x32x16 MFMA, BK=128): C = act(A @ Bt^T + bias) ----
// A, Bt PACKED. Tile 128x128, BK=128 (one vmcnt(0)+barrier drain per 128-k:
// half the drains of BK=64 — discriminating experiment vs L2-BW limit).
// LDS 64KB: As/Bs [kc 0..15][row 0..127][8]. 4 waves 2x2, wave tile 64x64 =
// 2x2 of 32x32x16. A/B frag: row=lane&31, k=(lane>>5)*8+[0..7].
// C/D frag: col=lane&31, row=(reg&3)+8*(reg>>2)+4*(lane>>5)  [m74/m101].
template <bool RELU_OUT_BF16>
__global__ __launch_bounds__(256) void gemm_kernel(
    const unsigned short* __restrict__ Ag, const unsigned short* __restrict__ Bt,
    const float* __restrict__ bias, void* __restrict__ Cptr, int M_valid, int K, int N) {
  __shared__ unsigned short As[16 * 128 * 8];  // 32 KB
  __shared__ unsigned short Bs[16 * 128 * 8];  // 32 KB

  // bijective XCD-chunked swizzle
  const int G = gridDim.x * gridDim.y;
  const int orig = blockIdx.y * gridDim.x + blockIdx.x;
  const int qq = G >> 3, rr = G & 7;
  const int xcd = orig & 7, loc = orig >> 3;
  const int wg = (xcd < rr ? xcd * (qq + 1) : rr * (qq + 1) + (xcd - rr) * qq) + loc;
  const int bx = wg % gridDim.x;
  const int by = wg / gridDim.x;

  const int tid = threadIdx.x;
  const int lane = tid & 63;
  const int wave = tid >> 6;
  const int wm = (wave >> 1) * 64;
  const int wn = (wave & 1) * 64;
  const int n0 = bx * 128;
  const int lane31 = lane & 31;
  const int kh = lane >> 5;  // 0..1

  const unsigned short* Apan = Ag + ((size_t)by * (K >> 3) << 10);
  const unsigned short* Bpan = Bt + ((size_t)bx * (K >> 3) << 10);

  f32x16 acc[2][2];
#pragma unroll
  for (int i = 0; i < 2; ++i)
#pragma unroll
    for (int j = 0; j < 2; ++j)
#pragma unroll
      for (int r = 0; r < 16; ++r) acc[i][j][r] = 0.f;

  for (int k0 = 0; k0 < K; k0 += 128) {
    // stage 128x128-k: 32 segments each of A and B; wave w takes s = w*8..w*8+7
#pragma unroll
    for (int ss = 0; ss < 8; ++ss) {
      int s = wave * 8 + ss;          // 0..31
      int rbase = (s & 1) * 64;
      int kca = (k0 >> 3) + (s >> 1); // 16 k-chunks
      gl_lds16(Apan + ((size_t)kca << 10) + (rbase + lane) * 8, &As[s * 512]);
      gl_lds16(Bpan + ((size_t)kca << 10) + (rbase + lane) * 8, &Bs[s * 512]);
    }
    __syncthreads();

#pragma unroll
    for (int ks = 0; ks < 8; ++ks) {  // 8 x 16-k steps
      const int kc = ks * 2 + kh;
      bf16x8 af[2], bfr[2];
#pragma unroll
      for (int i = 0; i < 2; ++i)
        af[i] = *(const bf16x8*)&As[(kc * 128 + wm + i * 32 + lane31) * 8];
#pragma unroll
      for (int j = 0; j < 2; ++j)
        bfr[j] = *(const bf16x8*)&Bs[(kc * 128 + wn + j * 32 + lane31) * 8];
#pragma unroll
      for (int i = 0; i < 2; ++i)
#pragma unroll
        for (int j = 0; j < 2; ++j)
          acc[i][j] = __builtin_amdgcn_mfma_f32_32x32x16_bf16(af[i], bfr[j], acc[i][j], 0, 0, 0);
    }
    __syncthreads();
  }

  // epilogue: C/D layout col=lane&31, row=(r&3)+8*(r>>2)+4*kh
#pragma unroll
  for (int i = 0; i < 2; ++i) {
#pragma unroll
    for (int j = 0; j < 2; ++j) {
      const int gn = n0 + wn + j * 32 + lane31;
      const float bv = bias[gn];
#pragma unroll
      for (int r = 0; r < 16; ++r) {
        const int lr = wm + i * 32 + 4 * kh + (r & 3) + 8 * (r >> 2);
        float v = acc[i][j][r] + bv;
        if constexpr (RELU_OUT_BF16) {
          v = fmaxf(v, 0.f);
          size_t a = (((size_t)by * (N >> 3) + (gn >> 3)) << 10) + (lr << 3) + (gn & 7);
          ((unsigned short*)Cptr)[a] = f2bf(v);
        } else {
          int gm = by * 128 + lr;
          if (gm < M_valid) ((float*)Cptr)[(size_t)gm * N + gn] = v;
        }
      }
    }
  }
}

extern "C" void kernel_launch(void* const* d_in, const int* in_sizes, int n_in,
                              void* d_out, int out_size, void* d_ws, size_t ws_size,
                              hipStream_t stream) {
  const float* x    = (const float*)d_in[0];
  const int*   ei   = (const int*)d_in[1];
  const float* cond = (const float*)d_in[2];
  const float* Wk   = (const float*)d_in[3];
  const float* W1   = (const float*)d_in[4];
  const float* b1   = (const float*)d_in[5];
  const float* W2   = (const float*)d_in[6];
  const float* b2   = (const float*)d_in[7];
  float* out = (float*)d_out;

  char* ws = (char*)d_ws;
  size_t off = 0;
  auto alloc = [&](size_t b) { size_t p = off; off += (b + 255) & ~(size_t)255; return p; };
  float* key = (float*)(ws + alloc(2 * D * sizeof(float)));
  float* nki = (float*)(ws + alloc(NNODES * sizeof(float)));
  float* nkj = (float*)(ws + alloc(NNODES * sizeof(float)));
  int* deg    = (int*)(ws + alloc(NNODES * sizeof(int)));
  int* rowptr = (int*)(ws + alloc((NNODES + 1) * sizeof(int)));
  int* cursor = (int*)(ws + alloc(NNODES * sizeof(int)));
  int* blktot = (int*)(ws + alloc(SCAN_BLOCKS * sizeof(int)));
  int* scol      = (int*)(ws + alloc(NEDGES * sizeof(int)));
  unsigned short* xb  = (unsigned short*)(ws + alloc((size_t)NNODES * D * 2));  // bf16 x, row-major
  unsigned short* W1t = (unsigned short*)(ws + alloc((size_t)H1 * D * 2));      // packed (R=H1,K=D)
  unsigned short* W2t = (unsigned short*)(ws + alloc((size_t)D * H1 * 2));      // packed (R=D,K=H1)
  unsigned short* Pb  = (unsigned short*)(ws + alloc((size_t)MPAD * D * 2));    // packed (R=MPAD,K=D)
  unsigned short* Hb  = (unsigned short*)(ws + alloc((size_t)MPAD * H1 * 2));   // packed (R=MPAD,K=H1)

  const int* row = ei;
  const int* col = ei + NEDGES;

  hipMemsetAsync(deg, 0, NNODES * sizeof(int), stream);
  key_kernel<<<dim3(4), dim3(256), 0, stream>>>(cond, Wk, key);
  // fused: nodedot | convw | hist
  prep_kernel<<<dim3(NB_ND + NB_CW + NB_HI), dim3(256), 0, stream>>>(
      x, key, W1, W2, row, nki, nkj, xb, W1t, W2t, deg);

  scan1_kernel<<<dim3(SCAN_BLOCKS), dim3(256), 0, stream>>>(deg, rowptr, blktot);
  scan23_kernel<<<dim3(SCAN_BLOCKS), dim3(256), 0, stream>>>(rowptr, blktot, cursor);
  fill_kernel<<<dim3((NEDGES + 255) / 256), dim3(256), 0, stream>>>(row, col, cursor, scol);
  // aggregate: Pb = bf16(xb + segment_sum(alpha * xb[col])), alpha inline, packed
  agg_kernel<<<dim3(NB_ND), dim3(256), 0, stream>>>(xb, rowptr, scol, nki, nkj, Pb);

  // GEMM1: Hb = relu(Pb @ W1 + b1)  [M=50176, K=512, N=1024]  grid 8 x 392
  gemm_kernel<true><<<dim3(H1 / 128, MPAD / 128), dim3(256), 0, stream>>>(
      Pb, W1t, b1, Hb, NNODES, D, H1);
  // GEMM2: out = Hb @ W2 + b2       [M=50176, K=1024, N=512]  grid 4 x 392
  gemm_kernel<false><<<dim3(D / 128, MPAD / 128), dim3(256), 0, stream>>>(
      Hb, W2t, b2, out, NNODES, H1, D);
}

// Round 14
// 345.244 us; speedup vs baseline: 1.0457x; 1.0457x over previous
//
#include <hip/hip_runtime.h>

#define D 512
#define H1 1024
#define NNODES 50000
#define NEDGES 400000
#define MPAD 50176   // 392 * 128
#define NEG_SLOPE 0.2f
#define SCAN_BLOCKS 196   // 196*256 = 50176 >= 50000

// prep kernel block partition
#define NB_ND 12500   // nodedot: 50000 waves
#define NB_CW 2048    // convw: 524288 elems
#define NB_HI 1563    // hist: 400128 threads

typedef __attribute__((ext_vector_type(8))) short bf16x8;
typedef __attribute__((ext_vector_type(8))) unsigned short u16x8;
typedef __attribute__((ext_vector_type(16))) float f32x16;

// packed operand layout for GEMM staging:
// addr(r, k) = ((r>>7)*(K>>3) + (k>>3))*1024 + (r&127)*8 + (k&7)
// -> a 64-lane global_load_lds segment (64 rows x one 8-k chunk) is one
//    contiguous 1KB burst; LDS image is linear and conflict-free.

__device__ __forceinline__ unsigned short f2bf(float f) {
  unsigned int u = __float_as_uint(f);
  unsigned int r = u + 0x7FFFu + ((u >> 16) & 1u);
  return (unsigned short)(r >> 16);
}
__device__ __forceinline__ float bf2f(unsigned short h) {
  return __uint_as_float((unsigned int)h << 16);
}

__device__ __forceinline__ void gl_lds16(const void* g, void* l) {
  __builtin_amdgcn_global_load_lds(
      (const __attribute__((address_space(1))) void*)g,
      (__attribute__((address_space(3))) void*)l, 16, 0, 0);
}

// key[j] = sum_i cond[i] * Wk[i][j],  Wk is (256, 2D) row-major
__global__ void key_kernel(const float* __restrict__ cond, const float* __restrict__ Wk,
                           float* __restrict__ key) {
  int j = blockIdx.x * blockDim.x + threadIdx.x;
  if (j >= 2 * D) return;
  float s = 0.f;
#pragma unroll 8
  for (int i = 0; i < 256; ++i) s += cond[i] * Wk[i * (2 * D) + j];
  key[j] = s;
}

// fused independent pre-work: nodedot | convw | hist  (key must be done; deg zeroed)
__global__ __launch_bounds__(256) void prep_kernel(
    const float* __restrict__ x, const float* __restrict__ key,
    const float* __restrict__ W1, const float* __restrict__ W2,
    const int* __restrict__ row,
    float* __restrict__ nki, float* __restrict__ nkj, unsigned short* __restrict__ xb,
    unsigned short* __restrict__ W1t, unsigned short* __restrict__ W2t,
    int* __restrict__ deg) {
  const int b = blockIdx.x;
  const int tid = threadIdx.x;
  if (b < NB_ND) {
    // ---- nodedot: one wave per node; also emit xb = bf16(x) row-major ----
    int wid = (b * 256 + tid) >> 6;
    int lane = tid & 63;
    const float4* xr = (const float4*)(x + (size_t)wid * D);
    float4 p0 = xr[2 * lane], p1 = xr[2 * lane + 1];
    const float4* kia = (const float4*)key;
    const float4* kja = (const float4*)(key + D);
    float4 q0 = kia[2 * lane], q1 = kia[2 * lane + 1];
    float4 r0 = kja[2 * lane], r1 = kja[2 * lane + 1];
    float a = p0.x * q0.x + p0.y * q0.y + p0.z * q0.z + p0.w * q0.w +
              p1.x * q1.x + p1.y * q1.y + p1.z * q1.z + p1.w * q1.w;
    float bb = p0.x * r0.x + p0.y * r0.y + p0.z * r0.z + p0.w * r0.w +
               p1.x * r1.x + p1.y * r1.y + p1.z * r1.z + p1.w * r1.w;
    u16x8 h;
    h[0] = f2bf(p0.x); h[1] = f2bf(p0.y); h[2] = f2bf(p0.z); h[3] = f2bf(p0.w);
    h[4] = f2bf(p1.x); h[5] = f2bf(p1.y); h[6] = f2bf(p1.z); h[7] = f2bf(p1.w);
    *(u16x8*)(xb + (size_t)wid * D + 8 * lane) = h;
#pragma unroll
    for (int off = 32; off > 0; off >>= 1) {
      a += __shfl_xor(a, off);
      bb += __shfl_xor(bb, off);
    }
    if (lane == 0) { nki[wid] = a; nkj[wid] = bb; }
  } else if (b < NB_ND + NB_CW) {
    // ---- convw: W1 -> W1t packed (R=H1,K=D); W2 -> W2t packed (R=D,K=H1) ----
    int idx = (b - NB_ND) * 256 + tid;
    {
      int k = idx / H1, n = idx % H1;
      size_t a = (((size_t)(n >> 7) * (D >> 3) + (k >> 3)) << 10) + ((n & 127) << 3) + (k & 7);
      W1t[a] = f2bf(W1[idx]);
    }
    {
      int k = idx / D, n = idx % D;
      size_t a = (((size_t)(n >> 7) * (H1 >> 3) + (k >> 3)) << 10) + ((n & 127) << 3) + (k & 7);
      W2t[a] = f2bf(W2[idx]);
    }
  } else {
    // ---- hist ----
    int e = (b - NB_ND - NB_CW) * 256 + tid;
    if (e < NEDGES) atomicAdd(&deg[row[e]], 1);
  }
}

// ---- CSR scans ----
__global__ void scan1_kernel(const int* __restrict__ deg, int* __restrict__ rowptr,
                             int* __restrict__ blktot) {
  __shared__ int s[256];
  int tid = threadIdx.x;
  int i = blockIdx.x * 256 + tid;
  int v = (i < NNODES) ? deg[i] : 0;
  s[tid] = v;
  __syncthreads();
#pragma unroll
  for (int off = 1; off < 256; off <<= 1) {
    int t = (tid >= off) ? s[tid - off] : 0;
    __syncthreads();
    s[tid] += t;
    __syncthreads();
  }
  if (i < NNODES) rowptr[i] = s[tid] - v;
  if (tid == 255) blktot[blockIdx.x] = s[255];
}

// fused scan2+scan3: every block redundantly scans the 196 block totals,
// takes its own exclusive offset, applies to rowptr and inits cursor.
__global__ void scan23_kernel(int* __restrict__ rowptr, const int* __restrict__ blktot,
                              int* __restrict__ cursor) {
  __shared__ int s[256];
  int tid = threadIdx.x;
  int v = (tid < SCAN_BLOCKS) ? blktot[tid] : 0;
  s[tid] = v;
  __syncthreads();
#pragma unroll
  for (int off = 1; off < 256; off <<= 1) {
    int t = (tid >= off) ? s[tid - off] : 0;
    __syncthreads();
    s[tid] += t;
    __syncthreads();
  }
  const int blkoff = s[blockIdx.x] - blktot[blockIdx.x];  // exclusive
  int i = blockIdx.x * 256 + tid;
  if (i < NNODES) {
    int val = rowptr[i] + blkoff;
    rowptr[i] = val;
    cursor[i] = val;
  }
  if (i == 0) rowptr[NNODES] = NEDGES;
}

// fill: compute alpha (absorbs the random nki/nkj gathers) + CSR permutation
__global__ void fill_kernel(const int* __restrict__ row, const int* __restrict__ col,
                            const float* __restrict__ nki, const float* __restrict__ nkj,
                            int* __restrict__ cursor, int* __restrict__ scol,
                            float* __restrict__ salpha) {
  int e = blockIdx.x * blockDim.x + threadIdx.x;
  if (e >= NEDGES) return;
  int r = row[e], c = col[e];
  float a = nki[c] + nkj[r];
  a = (a >= 0.f) ? a : NEG_SLOPE * a;
  float al = 1.f / (1.f + expf(-a));
  int pos = atomicAdd(&cursor[r], 1);
  scol[pos] = c;
  salpha[pos] = al;
}

// one wave per node: Pb[n] = bf16(xb[n] + sum_e salpha_e * xb[scol[e]]), packed out.
// unroll x4: 4 independent gather chains + 4 accumulator sets (latency hiding).
__global__ __launch_bounds__(256) void agg_kernel(
    const unsigned short* __restrict__ xb, const int* __restrict__ rowptr,
    const int* __restrict__ scol, const float* __restrict__ salpha,
    unsigned short* __restrict__ Pb) {
  int n = (blockIdx.x * blockDim.x + threadIdx.x) >> 6;
  int lane = threadIdx.x & 63;
  if (n >= NNODES) return;
  int beg = rowptr[n], end = rowptr[n + 1];
  u16x8 self = *(const u16x8*)(xb + (size_t)n * D + 8 * lane);
  float s0[8], s1[8], s2[8], s3[8];
#pragma unroll
  for (int q = 0; q < 8; ++q) { s0[q] = bf2f(self[q]); s1[q] = 0.f; s2[q] = 0.f; s3[q] = 0.f; }
  int e = beg;
  for (; e + 3 < end; e += 4) {
    int c0 = scol[e], c1 = scol[e + 1], c2 = scol[e + 2], c3 = scol[e + 3];
    float a0 = salpha[e], a1 = salpha[e + 1], a2 = salpha[e + 2], a3 = salpha[e + 3];
    u16x8 w0 = *(const u16x8*)(xb + (size_t)c0 * D + 8 * lane);
    u16x8 w1 = *(const u16x8*)(xb + (size_t)c1 * D + 8 * lane);
    u16x8 w2 = *(const u16x8*)(xb + (size_t)c2 * D + 8 * lane);
    u16x8 w3 = *(const u16x8*)(xb + (size_t)c3 * D + 8 * lane);
#pragma unroll
    for (int q = 0; q < 8; ++q) {
      s0[q] += a0 * bf2f(w0[q]);
      s1[q] += a1 * bf2f(w1[q]);
      s2[q] += a2 * bf2f(w2[q]);
      s3[q] += a3 * bf2f(w3[q]);
    }
  }
  for (; e < end; ++e) {
    int c0 = scol[e];
    float a0 = salpha[e];
    u16x8 w0 = *(const u16x8*)(xb + (size_t)c0 * D + 8 * lane);
#pragma unroll
    for (int q = 0; q < 8; ++q) s0[q] += a0 * bf2f(w0[q]);
  }
  u16x8 h;
#pragma unroll
  for (int q = 0; q < 8; ++q) h[q] = f2bf((s0[q] + s1[q]) + (s2[q] + s3[q]));
  *(u16x8*)(Pb + (((size_t)(n >> 7) * (D >> 3) + lane) << 10) + ((n & 127) << 3)) = h;
}

// ---- GEMM (m97 structure, 32x32x16 MFMA, BK=64 — R12 proven): ----
// C = act(A @ Bt^T + bias). A, Bt PACKED. Tile 128x128, global_load_lds x16
// into linear chunked LDS [kc][row][8], 4 waves 2x2, wave tile 64x64 = 2x2 of
// 32x32x16 MFMA. A/B frag: row(col)=lane&31, k=(lane>>5)*8+[0..7].
// C/D frag: col=lane&31, row=(reg&3)+8*(reg>>2)+4*(lane>>5)  [m74/m101].
template <bool RELU_OUT_BF16>
__global__ __launch_bounds__(256) void gemm_kernel(
    const unsigned short* __restrict__ Ag, const unsigned short* __restrict__ Bt,
    const float* __restrict__ bias, void* __restrict__ Cptr, int M_valid, int K, int N) {
  __shared__ unsigned short As[8 * 128 * 8];  // [kc][row][8], 16 KB
  __shared__ unsigned short Bs[8 * 128 * 8];

  // bijective XCD-chunked swizzle
  const int G = gridDim.x * gridDim.y;
  const int orig = blockIdx.y * gridDim.x + blockIdx.x;
  const int qq = G >> 3, rr = G & 7;
  const int xcd = orig & 7, loc = orig >> 3;
  const int wg = (xcd < rr ? xcd * (qq + 1) : rr * (qq + 1) + (xcd - rr) * qq) + loc;
  const int bx = wg % gridDim.x;
  const int by = wg / gridDim.x;

  const int tid = threadIdx.x;
  const int lane = tid & 63;
  const int wave = tid >> 6;
  const int wm = (wave >> 1) * 64;
  const int wn = (wave & 1) * 64;
  const int n0 = bx * 128;
  const int lane31 = lane & 31;
  const int kh = lane >> 5;  // 0..1

  const unsigned short* Apan = Ag + ((size_t)by * (K >> 3) << 10);
  const unsigned short* Bpan = Bt + ((size_t)bx * (K >> 3) << 10);

  f32x16 acc[2][2];
#pragma unroll
  for (int i = 0; i < 2; ++i)
#pragma unroll
    for (int j = 0; j < 2; ++j)
#pragma unroll
      for (int r = 0; r < 16; ++r) acc[i][j][r] = 0.f;

  for (int k0 = 0; k0 < K; k0 += 64) {
#pragma unroll
    for (int ss = 0; ss < 4; ++ss) {
      int s = wave * 4 + ss;
      int rbase = (s & 1) * 64;
      int kca = (k0 >> 3) + (s >> 1);
      gl_lds16(Apan + ((size_t)kca << 10) + (rbase + lane) * 8, &As[s * 512]);
      gl_lds16(Bpan + ((size_t)kca << 10) + (rbase + lane) * 8, &Bs[s * 512]);
    }
    __syncthreads();

#pragma unroll
    for (int ks = 0; ks < 4; ++ks) {  // 16-k steps
      const int kc = ks * 2 + kh;
      bf16x8 af[2], bfr[2];
#pragma unroll
      for (int i = 0; i < 2; ++i)
        af[i] = *(const bf16x8*)&As[(kc * 128 + wm + i * 32 + lane31) * 8];
#pragma unroll
      for (int j = 0; j < 2; ++j)
        bfr[j] = *(const bf16x8*)&Bs[(kc * 128 + wn + j * 32 + lane31) * 8];
#pragma unroll
      for (int i = 0; i < 2; ++i)
#pragma unroll
        for (int j = 0; j < 2; ++j)
          acc[i][j] = __builtin_amdgcn_mfma_f32_32x32x16_bf16(af[i], bfr[j], acc[i][j], 0, 0, 0);
    }
    __syncthreads();
  }

  // epilogue: C/D layout col=lane&31, row=(r&3)+8*(r>>2)+4*kh
#pragma unroll
  for (int i = 0; i < 2; ++i) {
#pragma unroll
    for (int j = 0; j < 2; ++j) {
      const int gn = n0 + wn + j * 32 + lane31;
      const float bv = bias[gn];
#pragma unroll
      for (int r = 0; r < 16; ++r) {
        const int lr = wm + i * 32 + 4 * kh + (r & 3) + 8 * (r >> 2);
        float v = acc[i][j][r] + bv;
        if constexpr (RELU_OUT_BF16) {
          v = fmaxf(v, 0.f);
          size_t a = (((size_t)by * (N >> 3) + (gn >> 3)) << 10) + (lr << 3) + (gn & 7);
          ((unsigned short*)Cptr)[a] = f2bf(v);
        } else {
          int gm = by * 128 + lr;
          if (gm < M_valid) ((float*)Cptr)[(size_t)gm * N + gn] = v;
        }
      }
    }
  }
}

extern "C" void kernel_launch(void* const* d_in, const int* in_sizes, int n_in,
                              void* d_out, int out_size, void* d_ws, size_t ws_size,
                              hipStream_t stream) {
  const float* x    = (const float*)d_in[0];
  const int*   ei   = (const int*)d_in[1];
  const float* cond = (const float*)d_in[2];
  const float* Wk   = (const float*)d_in[3];
  const float* W1   = (const float*)d_in[4];
  const float* b1   = (const float*)d_in[5];
  const float* W2   = (const float*)d_in[6];
  const float* b2   = (const float*)d_in[7];
  float* out = (float*)d_out;

  char* ws = (char*)d_ws;
  size_t off = 0;
  auto alloc = [&](size_t b) { size_t p = off; off += (b + 255) & ~(size_t)255; return p; };
  float* key = (float*)(ws + alloc(2 * D * sizeof(float)));
  float* nki = (float*)(ws + alloc(NNODES * sizeof(float)));
  float* nkj = (float*)(ws + alloc(NNODES * sizeof(float)));
  int* deg    = (int*)(ws + alloc(NNODES * sizeof(int)));
  int* rowptr = (int*)(ws + alloc((NNODES + 1) * sizeof(int)));
  int* cursor = (int*)(ws + alloc(NNODES * sizeof(int)));
  int* blktot = (int*)(ws + alloc(SCAN_BLOCKS * sizeof(int)));
  int* scol      = (int*)(ws + alloc(NEDGES * sizeof(int)));
  float* salpha  = (float*)(ws + alloc(NEDGES * sizeof(float)));
  unsigned short* xb  = (unsigned short*)(ws + alloc((size_t)NNODES * D * 2));  // bf16 x, row-major
  unsigned short* W1t = (unsigned short*)(ws + alloc((size_t)H1 * D * 2));      // packed (R=H1,K=D)
  unsigned short* W2t = (unsigned short*)(ws + alloc((size_t)D * H1 * 2));      // packed (R=D,K=H1)
  unsigned short* Pb  = (unsigned short*)(ws + alloc((size_t)MPAD * D * 2));    // packed (R=MPAD,K=D)
  unsigned short* Hb  = (unsigned short*)(ws + alloc((size_t)MPAD * H1 * 2));   // packed (R=MPAD,K=H1)

  const int* row = ei;
  const int* col = ei + NEDGES;

  hipMemsetAsync(deg, 0, NNODES * sizeof(int), stream);
  key_kernel<<<dim3(4), dim3(256), 0, stream>>>(cond, Wk, key);
  // fused: nodedot | convw | hist
  prep_kernel<<<dim3(NB_ND + NB_CW + NB_HI), dim3(256), 0, stream>>>(
      x, key, W1, W2, row, nki, nkj, xb, W1t, W2t, deg);

  scan1_kernel<<<dim3(SCAN_BLOCKS), dim3(256), 0, stream>>>(deg, rowptr, blktot);
  scan23_kernel<<<dim3(SCAN_BLOCKS), dim3(256), 0, stream>>>(rowptr, blktot, cursor);
  fill_kernel<<<dim3((NEDGES + 255) / 256), dim3(256), 0, stream>>>(row, col, nki, nkj,
                                                                    cursor, scol, salpha);
  // aggregate: Pb = bf16(xb + segment_sum(salpha * xb[scol])), packed
  agg_kernel<<<dim3(NB_ND), dim3(256), 0, stream>>>(xb, rowptr, scol, salpha, Pb);

  // GEMM1: Hb = relu(Pb @ W1 + b1)  [M=50176, K=512, N=1024]  grid 8 x 392
  gemm_kernel<true><<<dim3(H1 / 128, MPAD / 128), dim3(256), 0, stream>>>(
      Pb, W1t, b1, Hb, NNODES, D, H1);
  // GEMM2: out = Hb @ W2 + b2       [M=50176, K=1024, N=512]  grid 4 x 392
  gemm_kernel<false><<<dim3(D / 128, MPAD / 128), dim3(256), 0, stream>>>(
      Hb, W2t, b2, out, NNODES, H1, D);
}